// Round 4
// baseline (11229.774 us; speedup 1.0000x reference)
//
#include <hip/hip_runtime.h>
#include <hip/hip_bf16.h>
#include <cstdint>

#define S_ 512
#define B_ 32
#define E_ 512
#define H_ 256
#define C_ 16

typedef float f32x4_t __attribute__((ext_vector_type(4)));
typedef __bf16 bf16x8_t __attribute__((ext_vector_type(8)));

__device__ __forceinline__ float bf2f(unsigned short u) {
    return __uint_as_float(((unsigned int)u) << 16);
}
__device__ __forceinline__ unsigned short f2bf(float f) {
    unsigned int u = __float_as_uint(f);
    unsigned int r = (u + 0x7FFFu + ((u >> 16) & 1u)) >> 16;
    return (unsigned short)r;
}
__device__ __forceinline__ float sigf(float x) { return 1.f / (1.f + __expf(-x)); }
__device__ __forceinline__ float tanhf_fast(float x) {
    float e = __expf(-2.f * fabsf(x));
    float r = (1.f - e) / (1.f + e);
    return x >= 0.f ? r : -r;
}

// ---------------- embedding gather -> bf16 X[s*32+b][0:512] ----------------
__global__ __launch_bounds__(128) void embed_gather(
    const int* __restrict__ x, const float* __restrict__ emb, unsigned short* __restrict__ X)
{
    int row = blockIdx.x;           // s*32 + b
    int s = row >> 5, b = row & 31;
    int idx = x[b * S_ + s];
    float4 v = ((const float4*)(emb + (size_t)idx * E_))[threadIdx.x];
    ushort4 o; o.x = f2bf(v.x); o.y = f2bf(v.y); o.z = f2bf(v.z); o.w = f2bf(v.w);
    ((ushort4*)(X + (size_t)row * E_))[threadIdx.x] = o;
}

// ---------------- f32 -> bf16 converter (n multiple of 4) ----------------
__global__ __launch_bounds__(256) void conv_f2b(
    const float* __restrict__ src, unsigned short* __restrict__ dst, int n)
{
    int i = (blockIdx.x * 256 + threadIdx.x) * 4;
    if (i < n) {
        float4 v = *(const float4*)(src + i);
        ushort4 o; o.x = f2bf(v.x); o.y = f2bf(v.y); o.z = f2bf(v.z); o.w = f2bf(v.w);
        *(ushort4*)(dst + i) = o;
    }
}

// ---------------- zero scratch ----------------
__global__ __launch_bounds__(256) void zero_ws(unsigned int* __restrict__ p, int n)
{
    int i = blockIdx.x * 256 + threadIdx.x;
    if (i < n) p[i] = 0u;
}

// ---------------- bf16 MFMA GEMM: C[M,N] = A[M,K] @ W[N,K]^T (+b1+b2) ----------------
// 64x64 tile, 256 thr (4 waves), BK=64. Wave w owns rows w*16..w*16+15.
template<int STORE_BF16>
__global__ __launch_bounds__(256) void gemm_bf16(
    const unsigned short* __restrict__ A, const unsigned short* __restrict__ W,
    const float* __restrict__ b1, const float* __restrict__ b2,
    void* __restrict__ Cout, int M, int N, int K)
{
    __shared__ __align__(16) char lds[16384];   // A-tile 8K + W-tile 8K, swizzled
    char* asb = lds;
    char* wsb = lds + 8192;
    const int tid = threadIdx.x;
    const int m0 = blockIdx.x * 64, n0 = blockIdx.y * 64;
    const int w = tid >> 6, L = tid & 63;
    const int sr = tid >> 2, sq = tid & 3;
    const int mrow = L & 15, kg = (L >> 4) * 8;
    f32x4_t acc[4];
    #pragma unroll
    for (int ni = 0; ni < 4; ++ni) acc[ni] = f32x4_t{0.f, 0.f, 0.f, 0.f};

    for (int k0 = 0; k0 < K; k0 += 64) {
        uint4 av1 = *(const uint4*)(A + (size_t)(m0 + sr) * K + k0 + sq * 16);
        uint4 av2 = *(const uint4*)(A + (size_t)(m0 + sr) * K + k0 + sq * 16 + 8);
        uint4 wv1 = *(const uint4*)(W + (size_t)(n0 + sr) * K + k0 + sq * 16);
        uint4 wv2 = *(const uint4*)(W + (size_t)(n0 + sr) * K + k0 + sq * 16 + 8);
        __syncthreads();
        int sw = (sr & 7) << 4;
        *(uint4*)(asb + ((sr * 128 + sq * 32) ^ sw))      = av1;
        *(uint4*)(asb + ((sr * 128 + sq * 32 + 16) ^ sw)) = av2;
        *(uint4*)(wsb + ((sr * 128 + sq * 32) ^ sw))      = wv1;
        *(uint4*)(wsb + ((sr * 128 + sq * 32 + 16) ^ sw)) = wv2;
        __syncthreads();
        #pragma unroll
        for (int kb = 0; kb < 2; ++kb) {
            int kl = kb * 32 + kg;
            int ar = w * 16 + mrow;
            bf16x8_t a = *(const bf16x8_t*)(asb + ((ar * 128 + kl * 2) ^ ((ar & 7) << 4)));
            #pragma unroll
            for (int ni = 0; ni < 4; ++ni) {
                int nr = ni * 16 + mrow;
                bf16x8_t b = *(const bf16x8_t*)(wsb + ((nr * 128 + kl * 2) ^ ((nr & 7) << 4)));
                acc[ni] = __builtin_amdgcn_mfma_f32_16x16x32_bf16(a, b, acc[ni], 0, 0, 0);
            }
        }
    }
    #pragma unroll
    for (int ni = 0; ni < 4; ++ni) {
        int n = n0 + ni * 16 + mrow;
        float bb = (b1 ? b1[n] : 0.f) + (b2 ? b2[n] : 0.f);
        #pragma unroll
        for (int r = 0; r < 4; ++r) {
            int m = m0 + w * 16 + (L >> 4) * 4 + r;
            float v = acc[ni][r] + bb;
            size_t off = (size_t)m * N + n;
            if (STORE_BF16) ((unsigned short*)Cout)[off] = f2bf(v);
            else            ((float*)Cout)[off] = v;
        }
    }
}

// ---------------- LSTM recurrence v2: 4 blocks = 2 dir x 2 halves, weights in VGPRs ----
// Block: 512 thr (8 waves, 2/SIMD, 256 VGPR budget = full CU RF). Each block owns 128
// units x 4 gates = 512 rows x 256 k bf16 = 256 KB held entirely in registers
// (128 VGPR/lane of B-fragments). LDS holds only h [32 b][256 u] bf16 swizzled (16 KB).
// Cross-block h exchange: tagged {tag, h-pair} 8-byte relaxed atomics, parity
// double-buffered, monotone tags (tagbase per layer) -> no flags, no drain barrier.
__global__ __launch_bounds__(512) void lstm_rec2(
    const unsigned short* __restrict__ Zf,
    const unsigned short* __restrict__ Zb,
    const unsigned short* __restrict__ whhb,   // [2 dir][1024][256] bf16 (this layer)
    unsigned long long* __restrict__ hglob,    // [2 dir][2 par][32 b][128 upair], pre-zeroed
    unsigned int tagbase,
    unsigned short* __restrict__ Hb)           // [16384][512] bf16
{
    __shared__ __align__(16) char lds[16384];
    const int tid = threadIdx.x;
    const int d = blockIdx.x >> 1;
    const int p = blockIdx.x & 1;
    const int w = tid >> 6, L = tid & 63;
    const int mrow = L & 15;
    const int kg8 = (L >> 4) * 8;
    const int swz = (mrow & 7) << 4;
    const int u = p * 128 + w * 16 + mrow;       // owned unit (global, 0..255)
    const unsigned short* Z = d ? Zb : Zf;
    unsigned long long* hgd = hglob + (size_t)d * 8192;

    // ---- one-time: load all owned weight fragments into registers ----
    // wreg[g][j]: j in [0,4) = own k-tiles (p*4+j), j in [4,8) = peer k-tiles
    bf16x8_t wreg[4][8];
    #pragma unroll
    for (int g = 0; g < 4; ++g)
        #pragma unroll
        for (int j = 0; j < 8; ++j) {
            int kt = (j < 4) ? (p * 4 + j) : ((1 - p) * 4 + (j - 4));
            wreg[g][j] = *(const bf16x8_t*)(
                whhb + ((size_t)d * 1024 + g * 256 + u) * 256 + kt * 32 + kg8);
        }
    float cst[8] = {0.f, 0.f, 0.f, 0.f, 0.f, 0.f, 0.f, 0.f};

    for (int tt = 0; tt < 512; ++tt) {
        const int t = d ? (511 - tt) : tt;

        // prefetch Zx: 4 gates x 8 (b) for this lane's unit u
        unsigned short zxv[4][8];
        #pragma unroll
        for (int g = 0; g < 4; ++g)
            #pragma unroll
            for (int j = 0; j < 8; ++j) {
                int b = (j >> 2) * 16 + (L >> 4) * 4 + (j & 3);
                zxv[g][j] = Z[((size_t)t * 32 + b) * 1024 + g * 256 + u];
            }

        f32x4_t acc[4][2];
        #pragma unroll
        for (int g = 0; g < 4; ++g) {
            acc[g][0] = f32x4_t{0.f, 0.f, 0.f, 0.f};
            acc[g][1] = f32x4_t{0.f, 0.f, 0.f, 0.f};
        }

        if (tt > 0) {
            // ---- MFMA over own k-half (h written to LDS at end of prev step) ----
            #pragma unroll
            for (int kk = 0; kk < 4; ++kk) {
                int kb = (p * 4 + kk) * 32 + kg8;
                bf16x8_t a0 = *(const bf16x8_t*)(lds + ((mrow * 512 + kb * 2) ^ swz));
                bf16x8_t a1 = *(const bf16x8_t*)(lds + (((mrow + 16) * 512 + kb * 2) ^ swz));
                #pragma unroll
                for (int g = 0; g < 4; ++g) {
                    acc[g][0] = __builtin_amdgcn_mfma_f32_16x16x32_bf16(a0, wreg[g][kk], acc[g][0], 0, 0, 0);
                    acc[g][1] = __builtin_amdgcn_mfma_f32_16x16x32_bf16(a1, wreg[g][kk], acc[g][1], 0, 0, 0);
                }
            }
            // ---- poll peer's tagged words (4 per thread), stage to LDS ----
            {
                unsigned long long* slot = hgd + (size_t)((tt + 1) & 1) * 4096;
                const int pb = (1 - p) * 64;
                const unsigned int expt = tagbase + (unsigned int)tt;
                int l0 = tid, l1 = 512 + tid, l2 = 1024 + tid, l3 = 1536 + tid;
                unsigned long long* a0p = slot + (l0 >> 6) * 128 + pb + (l0 & 63);
                unsigned long long* a1p = slot + (l1 >> 6) * 128 + pb + (l1 & 63);
                unsigned long long* a2p = slot + (l2 >> 6) * 128 + pb + (l2 & 63);
                unsigned long long* a3p = slot + (l3 >> 6) * 128 + pb + (l3 & 63);
                unsigned long long v0, v1, v2, v3;
                for (;;) {
                    v0 = __hip_atomic_load(a0p, __ATOMIC_RELAXED, __HIP_MEMORY_SCOPE_AGENT);
                    v1 = __hip_atomic_load(a1p, __ATOMIC_RELAXED, __HIP_MEMORY_SCOPE_AGENT);
                    v2 = __hip_atomic_load(a2p, __ATOMIC_RELAXED, __HIP_MEMORY_SCOPE_AGENT);
                    v3 = __hip_atomic_load(a3p, __ATOMIC_RELAXED, __HIP_MEMORY_SCOPE_AGENT);
                    if (((unsigned int)v0 == expt) & ((unsigned int)v1 == expt) &
                        ((unsigned int)v2 == expt) & ((unsigned int)v3 == expt)) break;
                    __builtin_amdgcn_s_sleep(1);
                }
                int ub2 = (1 - p) * 128;
                {
                    int b = l0 >> 6, uu = ub2 + (l0 & 63) * 2;
                    *(unsigned int*)(lds + ((b * 512 + uu * 2) ^ ((b & 7) << 4))) = (unsigned int)(v0 >> 32);
                }
                {
                    int b = l1 >> 6, uu = ub2 + (l1 & 63) * 2;
                    *(unsigned int*)(lds + ((b * 512 + uu * 2) ^ ((b & 7) << 4))) = (unsigned int)(v1 >> 32);
                }
                {
                    int b = l2 >> 6, uu = ub2 + (l2 & 63) * 2;
                    *(unsigned int*)(lds + ((b * 512 + uu * 2) ^ ((b & 7) << 4))) = (unsigned int)(v2 >> 32);
                }
                {
                    int b = l3 >> 6, uu = ub2 + (l3 & 63) * 2;
                    *(unsigned int*)(lds + ((b * 512 + uu * 2) ^ ((b & 7) << 4))) = (unsigned int)(v3 >> 32);
                }
            }
            __syncthreads();
            // ---- MFMA over peer k-half ----
            #pragma unroll
            for (int kk = 0; kk < 4; ++kk) {
                int kb = ((1 - p) * 4 + kk) * 32 + kg8;
                bf16x8_t a0 = *(const bf16x8_t*)(lds + ((mrow * 512 + kb * 2) ^ swz));
                bf16x8_t a1 = *(const bf16x8_t*)(lds + (((mrow + 16) * 512 + kb * 2) ^ swz));
                #pragma unroll
                for (int g = 0; g < 4; ++g) {
                    acc[g][0] = __builtin_amdgcn_mfma_f32_16x16x32_bf16(a0, wreg[g][4 + kk], acc[g][0], 0, 0, 0);
                    acc[g][1] = __builtin_amdgcn_mfma_f32_16x16x32_bf16(a1, wreg[g][4 + kk], acc[g][1], 0, 0, 0);
                }
            }
        }

        // ---- gates in-register ----
        float hh[8];
        #pragma unroll
        for (int mh = 0; mh < 2; ++mh)
            #pragma unroll
            for (int r = 0; r < 4; ++r) {
                int j = mh * 4 + r;
                float iv = sigf(acc[0][mh][r] + bf2f(zxv[0][j]));
                float fv = sigf(acc[1][mh][r] + bf2f(zxv[1][j]));
                float gv = tanhf_fast(acc[2][mh][r] + bf2f(zxv[2][j]));
                float ov = sigf(acc[3][mh][r] + bf2f(zxv[3][j]));
                cst[j] = fv * cst[j] + iv * gv;
                hh[j] = ov * tanhf_fast(cst[j]);
            }

        // ---- pack pairs (shfl with lane^1) and publish + LDS own-h write + Hb ----
        {
            unsigned long long* oslot = hgd + (size_t)(tt & 1) * 4096;
            const int up = p * 64 + w * 8 + (mrow >> 1);
            const int ue = u & ~1;
            const unsigned long long tagw = (unsigned long long)(tagbase + (unsigned int)tt + 1u);
            #pragma unroll
            for (int j = 0; j < 8; ++j) {
                float ph = __shfl_xor(hh[j], 1);
                unsigned int mine = f2bf(hh[j]), othr = f2bf(ph);
                unsigned int pair = (L & 1) ? ((mine << 16) | othr) : ((othr << 16) | mine);
                if ((L & 1) == (j >> 2)) {
                    int b = (j >> 2) * 16 + (L >> 4) * 4 + (j & 3);
                    __hip_atomic_store(oslot + b * 128 + up,
                                       ((unsigned long long)pair << 32) | tagw,
                                       __ATOMIC_RELAXED, __HIP_MEMORY_SCOPE_AGENT);
                    *(unsigned int*)(lds + ((b * 512 + ue * 2) ^ ((b & 7) << 4))) = pair;
                    *(unsigned int*)(Hb + ((size_t)t * 32 + b) * 512 + d * 256 + ue) = pair;
                }
            }
        }
        __syncthreads();
    }
}

// ---------------- fused attention (bf16 in, bf16 out) ----------------
__global__ __launch_bounds__(256) void attn_fused(
    const unsigned short* __restrict__ qkv, unsigned short* __restrict__ outp)
{
    int s = blockIdx.x & 511;
    int h = blockIdx.x >> 9;
    __shared__ float qs[32][260];
    __shared__ float ks[32][260];
    __shared__ float vs[32][260];
    __shared__ float sc[32][36];
    int tid = threadIdx.x;
    for (int it = 0; it < 32; ++it) {
        const unsigned short* base = qkv + ((size_t)s * 32 + it) * 1536 + h * 256 + tid;
        qs[it][tid] = bf2f(base[0]);
        ks[it][tid] = bf2f(base[512]);
        vs[it][tid] = bf2f(base[1024]);
    }
    __syncthreads();
    int l = tid >> 3, m0 = (tid & 7) * 4;
    float a0 = 0, a1 = 0, a2 = 0, a3 = 0;
    for (int dd = 0; dd < 256; dd += 4) {
        float4 q4 = *(const float4*)&qs[l][dd];
        float4 k0v = *(const float4*)&ks[m0 + 0][dd];
        float4 k1v = *(const float4*)&ks[m0 + 1][dd];
        float4 k2v = *(const float4*)&ks[m0 + 2][dd];
        float4 k3v = *(const float4*)&ks[m0 + 3][dd];
        a0 += q4.x * k0v.x + q4.y * k0v.y + q4.z * k0v.z + q4.w * k0v.w;
        a1 += q4.x * k1v.x + q4.y * k1v.y + q4.z * k1v.z + q4.w * k1v.w;
        a2 += q4.x * k2v.x + q4.y * k2v.y + q4.z * k2v.z + q4.w * k2v.w;
        a3 += q4.x * k3v.x + q4.y * k3v.y + q4.z * k3v.z + q4.w * k3v.w;
    }
    sc[l][m0 + 0] = a0 * 0.0625f;
    sc[l][m0 + 1] = a1 * 0.0625f;
    sc[l][m0 + 2] = a2 * 0.0625f;
    sc[l][m0 + 3] = a3 * 0.0625f;
    __syncthreads();
    if (tid < 32) {
        float mx = -1e30f;
        for (int m = 0; m < 32; ++m) mx = fmaxf(mx, sc[tid][m]);
        float pr[32]; float sm = 0.f;
        for (int m = 0; m < 32; ++m) { pr[m] = __expf(sc[tid][m] - mx); sm += pr[m]; }
        float inv = 1.f / sm;
        for (int m = 0; m < 32; ++m) sc[tid][m] = pr[m] * inv;
    }
    __syncthreads();
    int l2 = tid >> 3, d0 = (tid & 7) * 32;
    float o[32] = {};
    for (int m = 0; m < 32; ++m) {
        float aw = sc[l2][m];
        #pragma unroll
        for (int dd = 0; dd < 32; dd += 4) {
            float4 v4 = *(const float4*)&vs[m][d0 + dd];
            o[dd] += aw * v4.x; o[dd + 1] += aw * v4.y; o[dd + 2] += aw * v4.z; o[dd + 3] += aw * v4.w;
        }
    }
    unsigned short* ob = outp + ((size_t)s * 32 + l2) * 512 + h * 256 + d0;
    #pragma unroll
    for (int dd = 0; dd < 32; dd += 4) {
        ushort4 pv;
        pv.x = f2bf(o[dd]); pv.y = f2bf(o[dd + 1]); pv.z = f2bf(o[dd + 2]); pv.w = f2bf(o[dd + 3]);
        *(ushort4*)(ob + dd) = pv;
    }
}

// ---------------- fc logits (A f32) ----------------
__global__ __launch_bounds__(256) void fc_logits(
    const float* __restrict__ A, const float* __restrict__ fcw, const float* __restrict__ fcb,
    float* __restrict__ outp)
{
    __shared__ float wsm[16][516];
    int tid = threadIdx.x;
    for (int idx = tid; idx < 8192; idx += 256) wsm[idx >> 9][idx & 511] = fcw[idx];
    __syncthreads();
    int r = blockIdx.x * 16 + (tid >> 4);
    int c = tid & 15;
    const float* ar = A + (size_t)r * 512;
    float acc = 0.f;
    for (int k = 0; k < 512; k += 4) {
        float4 a4 = *(const float4*)(ar + k);
        float4 w4 = *(const float4*)&wsm[c][k];
        acc += a4.x * w4.x + a4.y * w4.y + a4.z * w4.z + a4.w * w4.w;
    }
    int s = r >> 5, b = r & 31;
    outp[(size_t)b * 8192 + s * 16 + c] = acc + fcb[c];
}

// ---------------- CRF ----------------
__global__ __launch_bounds__(256) void crf_forward(
    const float* __restrict__ em, const int* __restrict__ labels,
    const float* __restrict__ cs, const float* __restrict__ ce, const float* __restrict__ ct,
    float* __restrict__ res)
{
    int b = blockIdx.x;
    int tid = threadIdx.x;
    int jj = tid >> 4, ii = tid & 15;
    __shared__ float trans[16][17];
    __shared__ float alpha[2][16];
    __shared__ float red[256];
    trans[tid >> 4][tid & 15] = ct[tid & 255];
    const float* emb_ = em + (size_t)b * 8192;
    const int* tg = labels + b * 512;
    float part = 0.f;
    for (int t = tid; t < 512; t += 256) {
        int cur = tg[t];
        part += emb_[t * 16 + cur] + (t == 0 ? cs[cur] : ct[tg[t - 1] * 16 + cur]);
    }
    red[tid] = part;
    if (tid < 16) alpha[0][tid] = cs[tid] + emb_[tid];
    __syncthreads();
    for (int off = 128; off > 0; off >>= 1) {
        if (tid < off) red[tid] += red[tid + off];
        __syncthreads();
    }
    for (int t = 1; t < 512; ++t) {
        int p = t & 1;
        float v = alpha[p ^ 1][ii] + trans[ii][jj];
        float mx = v;
        mx = fmaxf(mx, __shfl_xor(mx, 1));
        mx = fmaxf(mx, __shfl_xor(mx, 2));
        mx = fmaxf(mx, __shfl_xor(mx, 4));
        mx = fmaxf(mx, __shfl_xor(mx, 8));
        float e = __expf(v - mx);
        e += __shfl_xor(e, 1); e += __shfl_xor(e, 2); e += __shfl_xor(e, 4); e += __shfl_xor(e, 8);
        if (ii == 0) alpha[p][jj] = mx + __logf(e) + emb_[t * 16 + jj];
        __syncthreads();
    }
    if (tid == 0) {
        float mx = -1e30f;
        for (int c2 = 0; c2 < 16; ++c2) mx = fmaxf(mx, alpha[1][c2] + ce[c2]);
        float sm = 0.f;
        for (int c2 = 0; c2 < 16; ++c2) sm += __expf(alpha[1][c2] + ce[c2] - mx);
        float logZ = mx + __logf(sm);
        float score = red[0] + ce[tg[511]];
        res[b] = logZ - score;
    }
}

__global__ void crf_final(const float* __restrict__ res, float* __restrict__ nll)
{
    if (threadIdx.x == 0) {
        float s2 = 0.f;
        for (int b = 0; b < 32; ++b) s2 += res[b];
        nll[0] = s2;
    }
}

extern "C" void kernel_launch(void* const* d_in, const int* in_sizes, int n_in,
                              void* d_out, int out_size, void* d_ws, size_t ws_size,
                              hipStream_t stream)
{
    const int* x      = (const int*)d_in[0];
    const int* labels = (const int*)d_in[1];
    const float* emb  = (const float*)d_in[2];
    const float* wih  = (const float*)d_in[3];
    const float* whh  = (const float*)d_in[4];
    const float* bih  = (const float*)d_in[5];
    const float* bhh  = (const float*)d_in[6];
    const float* inw  = (const float*)d_in[7];
    const float* inb  = (const float*)d_in[8];
    const float* opw  = (const float*)d_in[9];
    const float* opb  = (const float*)d_in[10];
    const float* fcw  = (const float*)d_in[11];
    const float* fcb  = (const float*)d_in[12];
    const float* cs   = (const float*)d_in[13];
    const float* ce   = (const float*)d_in[14];
    const float* ct   = (const float*)d_in[15];
    float* out = (float*)d_out;

    // ws layout (MiB; max 120.2 used):
    //  [0,16)    Xb (embed out)       -> attnO (after qkv consumed)
    //  [16,48)   H0b [16,32)          -> OPout f32 [16,48) (after H1b dead); res at 16M (CRF)
    //  [32,48)   H1b
    //  [48,112)  Zfb [48,80), Zbb [80,112)   -> qkv [48,96) (after lstm-1)
    //  [112,120) wihb [112,116), whhb [116,118), inwb [118,119.5), opwb [119.5,120)
    //  [120,...) hg (128 KB tagged h-exchange)
    char* ws = (char*)d_ws;
    const size_t MiB = 1ull << 20;
    unsigned short* Xb    = (unsigned short*)(ws);
    unsigned short* attnO = (unsigned short*)(ws);
    unsigned short* H0b   = (unsigned short*)(ws + 16 * MiB);
    float*          OPout = (float*)(ws + 16 * MiB);
    float*          res   = (float*)(ws + 16 * MiB);
    unsigned short* H1b   = (unsigned short*)(ws + 32 * MiB);
    unsigned short* Zfb   = (unsigned short*)(ws + 48 * MiB);
    unsigned short* qkv   = (unsigned short*)(ws + 48 * MiB);
    unsigned short* Zbb   = (unsigned short*)(ws + 80 * MiB);
    unsigned short* wihb  = (unsigned short*)(ws + 112 * MiB);
    unsigned short* whhb  = (unsigned short*)(ws + 116 * MiB);
    unsigned short* inwb  = (unsigned short*)(ws + 118 * MiB);
    unsigned short* opwb  = (unsigned short*)(ws + 119 * MiB + 512 * 1024);
    unsigned long long* hg = (unsigned long long*)(ws + 120 * MiB);

    // 1) embedding gather + weight conversions + h-exchange zeroing
    embed_gather<<<16384, 128, 0, stream>>>(x, emb, Xb);
    conv_f2b<<<2048, 256, 0, stream>>>(wih, wihb, 2097152);
    conv_f2b<<<1024, 256, 0, stream>>>(whh, whhb, 1048576);
    conv_f2b<<<768, 256, 0, stream>>>(inw, inwb, 786432);
    conv_f2b<<<256, 256, 0, stream>>>(opw, opwb, 262144);
    zero_ws<<<128, 256, 0, stream>>>((unsigned int*)hg, 32768);

    // 2) two BiLSTM layers
    for (int l = 0; l < 2; ++l) {
        const unsigned short* Ain = l ? H0b : Xb;
        unsigned short* Ho        = l ? H1b : H0b;
        for (int dd = 0; dd < 2; ++dd) {
            gemm_bf16<1><<<dim3(256, 16), 256, 0, stream>>>(
                Ain, wihb + (size_t)(l * 2 + dd) * 524288,
                bih + (l * 2 + dd) * 1024, bhh + (l * 2 + dd) * 1024,
                dd ? (void*)Zbb : (void*)Zfb, 16384, 1024, 512);
        }
        lstm_rec2<<<4, 512, 0, stream>>>(
            Zfb, Zbb, whhb + (size_t)l * 524288, hg, (unsigned int)(l * 512), Ho);
    }

    // 3) MHA
    gemm_bf16<1><<<dim3(256, 24), 256, 0, stream>>>(H1b, inwb, inb, nullptr, (void*)qkv, 16384, 1536, 512);
    attn_fused<<<1024, 256, 0, stream>>>(qkv, attnO);
    gemm_bf16<0><<<dim3(256, 8), 256, 0, stream>>>(attnO, opwb, opb, nullptr, (void*)OPout, 16384, 512, 512);

    // 4) logits -> d_out
    fc_logits<<<1024, 256, 0, stream>>>(OPout, fcw, fcb, out);

    // 5) CRF
    crf_forward<<<32, 256, 0, stream>>>(out, labels, cs, ce, ct, res);
    crf_final<<<1, 64, 0, stream>>>(res, out + 262144);

    (void)in_sizes; (void)n_in; (void)out_size; (void)ws_size;
}

// Round 5
// 7618.860 us; speedup vs baseline: 1.4739x; 1.4739x over previous
//
#include <hip/hip_runtime.h>
#include <hip/hip_bf16.h>
#include <cstdint>

#define S_ 512
#define B_ 32
#define E_ 512
#define H_ 256
#define C_ 16

typedef float f32x4_t __attribute__((ext_vector_type(4)));
typedef __bf16 bf16x8_t __attribute__((ext_vector_type(8)));

__device__ __forceinline__ float bf2f(unsigned short u) {
    return __uint_as_float(((unsigned int)u) << 16);
}
__device__ __forceinline__ unsigned short f2bf(float f) {
    unsigned int u = __float_as_uint(f);
    unsigned int r = (u + 0x7FFFu + ((u >> 16) & 1u)) >> 16;
    return (unsigned short)r;
}
__device__ __forceinline__ float sigf(float x) { return 1.f / (1.f + __expf(-x)); }
__device__ __forceinline__ float tanhf_fast(float x) {
    float e = __expf(-2.f * fabsf(x));
    float r = (1.f - e) / (1.f + e);
    return x >= 0.f ? r : -r;
}

// ---------------- embedding gather -> bf16 X[s*32+b][0:512] ----------------
__global__ __launch_bounds__(128) void embed_gather(
    const int* __restrict__ x, const float* __restrict__ emb, unsigned short* __restrict__ X)
{
    int row = blockIdx.x;           // s*32 + b
    int s = row >> 5, b = row & 31;
    int idx = x[b * S_ + s];
    float4 v = ((const float4*)(emb + (size_t)idx * E_))[threadIdx.x];
    ushort4 o; o.x = f2bf(v.x); o.y = f2bf(v.y); o.z = f2bf(v.z); o.w = f2bf(v.w);
    ((ushort4*)(X + (size_t)row * E_))[threadIdx.x] = o;
}

// ---------------- f32 -> bf16 converter (n multiple of 4) ----------------
__global__ __launch_bounds__(256) void conv_f2b(
    const float* __restrict__ src, unsigned short* __restrict__ dst, int n)
{
    int i = (blockIdx.x * 256 + threadIdx.x) * 4;
    if (i < n) {
        float4 v = *(const float4*)(src + i);
        ushort4 o; o.x = f2bf(v.x); o.y = f2bf(v.y); o.z = f2bf(v.z); o.w = f2bf(v.w);
        *(ushort4*)(dst + i) = o;
    }
}

// ---------------- zero scratch ----------------
__global__ __launch_bounds__(256) void zero_ws(unsigned int* __restrict__ p, int n)
{
    int i = blockIdx.x * 256 + threadIdx.x;
    if (i < n) p[i] = 0u;
}

// ---------------- bf16 MFMA GEMM: C[M,N] = A[M,K] @ W[N,K]^T (+b1+b2) ----------------
// 64x64 tile, 256 thr (4 waves), BK=64. Wave w owns rows w*16..w*16+15.
template<int STORE_BF16>
__global__ __launch_bounds__(256) void gemm_bf16(
    const unsigned short* __restrict__ A, const unsigned short* __restrict__ W,
    const float* __restrict__ b1, const float* __restrict__ b2,
    void* __restrict__ Cout, int M, int N, int K)
{
    __shared__ __align__(16) char lds[16384];   // A-tile 8K + W-tile 8K, swizzled
    char* asb = lds;
    char* wsb = lds + 8192;
    const int tid = threadIdx.x;
    const int m0 = blockIdx.x * 64, n0 = blockIdx.y * 64;
    const int w = tid >> 6, L = tid & 63;
    const int sr = tid >> 2, sq = tid & 3;
    const int mrow = L & 15, kg = (L >> 4) * 8;
    f32x4_t acc[4];
    #pragma unroll
    for (int ni = 0; ni < 4; ++ni) acc[ni] = f32x4_t{0.f, 0.f, 0.f, 0.f};

    for (int k0 = 0; k0 < K; k0 += 64) {
        uint4 av1 = *(const uint4*)(A + (size_t)(m0 + sr) * K + k0 + sq * 16);
        uint4 av2 = *(const uint4*)(A + (size_t)(m0 + sr) * K + k0 + sq * 16 + 8);
        uint4 wv1 = *(const uint4*)(W + (size_t)(n0 + sr) * K + k0 + sq * 16);
        uint4 wv2 = *(const uint4*)(W + (size_t)(n0 + sr) * K + k0 + sq * 16 + 8);
        __syncthreads();
        int sw = (sr & 7) << 4;
        *(uint4*)(asb + ((sr * 128 + sq * 32) ^ sw))      = av1;
        *(uint4*)(asb + ((sr * 128 + sq * 32 + 16) ^ sw)) = av2;
        *(uint4*)(wsb + ((sr * 128 + sq * 32) ^ sw))      = wv1;
        *(uint4*)(wsb + ((sr * 128 + sq * 32 + 16) ^ sw)) = wv2;
        __syncthreads();
        #pragma unroll
        for (int kb = 0; kb < 2; ++kb) {
            int kl = kb * 32 + kg;
            int ar = w * 16 + mrow;
            bf16x8_t a = *(const bf16x8_t*)(asb + ((ar * 128 + kl * 2) ^ ((ar & 7) << 4)));
            #pragma unroll
            for (int ni = 0; ni < 4; ++ni) {
                int nr = ni * 16 + mrow;
                bf16x8_t b = *(const bf16x8_t*)(wsb + ((nr * 128 + kl * 2) ^ ((nr & 7) << 4)));
                acc[ni] = __builtin_amdgcn_mfma_f32_16x16x32_bf16(a, b, acc[ni], 0, 0, 0);
            }
        }
    }
    #pragma unroll
    for (int ni = 0; ni < 4; ++ni) {
        int n = n0 + ni * 16 + mrow;
        float bb = (b1 ? b1[n] : 0.f) + (b2 ? b2[n] : 0.f);
        #pragma unroll
        for (int r = 0; r < 4; ++r) {
            int m = m0 + w * 16 + (L >> 4) * 4 + r;
            float v = acc[ni][r] + bb;
            size_t off = (size_t)m * N + n;
            if (STORE_BF16) ((unsigned short*)Cout)[off] = f2bf(v);
            else            ((float*)Cout)[off] = v;
        }
    }
}

// ---------------- LSTM recurrence v3: 4 blocks = 2 dir x 2 halves ----------------
// Block: 512 thr (8 waves). Wave w owns units u = p*128 + w*16 + mrow (all 4 gates).
// Weights: own-k half (k in [p*128, p*128+128)) in REGISTERS (16 x bf16x8 = 64 VGPR);
// peer-k half in LDS (512 rows x 128 k bf16 = 128 KB, swizzled). h-buf 16 KB LDS.
// Cross-block h exchange: self-validating tagged {tag,lo | pair,hi} 8B relaxed atomics,
// parity double-buffered, monotone tags. __launch_bounds__(512,2) -> 256 VGPR cap.
__global__ __launch_bounds__(512, 2) void lstm_rec3(
    const unsigned short* __restrict__ Zf,
    const unsigned short* __restrict__ Zb,
    const unsigned short* __restrict__ whhb,   // [2 dir][1024][256] bf16 (this layer)
    unsigned long long* __restrict__ hglob,    // [2 dir][2 par][32 b][128 upair], pre-zeroed
    unsigned int tagbase,
    unsigned short* __restrict__ Hb)           // [16384][512] bf16
{
    __shared__ __align__(16) char lds[147456];  // weights 128K @0, h-buf 16K @131072
    char* hz = lds + 131072;
    const int tid = threadIdx.x;
    const int d = blockIdx.x >> 1;
    const int p = blockIdx.x & 1;
    const int w = tid >> 6, L = tid & 63;
    const int mrow = L & 15;
    const int kg8 = (L >> 4) * 8;
    const int swz = (mrow & 7) << 4;
    const int u = p * 128 + w * 16 + mrow;       // owned unit (global)
    const int peerk = (1 - p) * 128;             // peer k-range base
    const unsigned short* Z = d ? Zb : Zf;
    unsigned long long* hgd = hglob + (size_t)d * 8192;

    // ---- one-time: peer-k weight half -> LDS (rows = g*128+ul, 256B/row, swizzled) ----
    {
        #pragma unroll
        for (int i = 0; i < 16; ++i) {
            int c = i * 512 + tid;          // chunk id over 512 rows x 16 chunks
            int row = c >> 4, cc = c & 15;
            int g = row >> 7, ul = row & 127;
            uint4 wv = *(const uint4*)(
                whhb + ((size_t)d * 1024 + g * 256 + p * 128 + ul) * 256 + peerk + cc * 8);
            *(uint4*)(lds + ((row * 256 + cc * 16) ^ ((row & 7) << 4))) = wv;
        }
    }
    // ---- one-time: own-k weight half -> registers ----
    bf16x8_t wreg[4][4];
    #pragma unroll
    for (int g = 0; g < 4; ++g)
        #pragma unroll
        for (int kk = 0; kk < 4; ++kk)
            wreg[g][kk] = *(const bf16x8_t*)(
                whhb + ((size_t)d * 1024 + g * 256 + u) * 256 + p * 128 + kk * 32 + kg8);

    float cst[8] = {0.f, 0.f, 0.f, 0.f, 0.f, 0.f, 0.f, 0.f};
    __syncthreads();

    for (int tt = 0; tt < 512; ++tt) {
        const int t = d ? (511 - tt) : tt;

        // prefetch Zx: 4 gates x 8 (b) for this lane's unit u
        unsigned short zxv[4][8];
        #pragma unroll
        for (int g = 0; g < 4; ++g)
            #pragma unroll
            for (int j = 0; j < 8; ++j) {
                int b = (j >> 2) * 16 + (L >> 4) * 4 + (j & 3);
                zxv[g][j] = Z[((size_t)t * 32 + b) * 1024 + g * 256 + u];
            }

        f32x4_t acc[4][2];
        #pragma unroll
        for (int g = 0; g < 4; ++g) {
            acc[g][0] = f32x4_t{0.f, 0.f, 0.f, 0.f};
            acc[g][1] = f32x4_t{0.f, 0.f, 0.f, 0.f};
        }

        if (tt > 0) {
            // ---- MFMA over own k-half (weights in registers, h from LDS) ----
            #pragma unroll
            for (int kk = 0; kk < 4; ++kk) {
                int k0 = p * 128 + kk * 32 + kg8;
                bf16x8_t a0 = *(const bf16x8_t*)(hz + ((mrow * 512 + k0 * 2) ^ swz));
                bf16x8_t a1 = *(const bf16x8_t*)(hz + (((mrow + 16) * 512 + k0 * 2) ^ swz));
                #pragma unroll
                for (int g = 0; g < 4; ++g) {
                    acc[g][0] = __builtin_amdgcn_mfma_f32_16x16x32_bf16(a0, wreg[g][kk], acc[g][0], 0, 0, 0);
                    acc[g][1] = __builtin_amdgcn_mfma_f32_16x16x32_bf16(a1, wreg[g][kk], acc[g][1], 0, 0, 0);
                }
            }
            // ---- poll peer tagged words (4/thread, done-mask + backoff), stage to LDS ----
            {
                unsigned long long* slot = hgd + (size_t)((tt + 1) & 1) * 4096;
                const unsigned int expt = tagbase + (unsigned int)tt;
                const int pb = (1 - p) * 64;
                unsigned int dat[4];
                unsigned int done = 0;
                for (;;) {
                    #pragma unroll
                    for (int k = 0; k < 4; ++k) {
                        if (!(done & (1u << k))) {
                            int l = k * 512 + tid;
                            unsigned long long v = __hip_atomic_load(
                                slot + (l >> 6) * 128 + pb + (l & 63),
                                __ATOMIC_RELAXED, __HIP_MEMORY_SCOPE_AGENT);
                            if ((unsigned int)v == expt) { done |= (1u << k); dat[k] = (unsigned int)(v >> 32); }
                        }
                    }
                    if (done == 15u) break;
                    __builtin_amdgcn_s_sleep(2);
                }
                #pragma unroll
                for (int k = 0; k < 4; ++k) {
                    int l = k * 512 + tid;
                    int b = l >> 6, upl = l & 63;
                    int ubyte = (peerk + 2 * upl) * 2;
                    *(unsigned int*)(hz + ((b * 512 + ubyte) ^ ((b & 7) << 4))) = dat[k];
                }
            }
            __syncthreads();
            // ---- MFMA over peer k-half (weights from LDS) ----
            #pragma unroll
            for (int kk = 0; kk < 4; ++kk) {
                int krel = kk * 32 + kg8;
                int k0 = peerk + krel;
                bf16x8_t a0 = *(const bf16x8_t*)(hz + ((mrow * 512 + k0 * 2) ^ swz));
                bf16x8_t a1 = *(const bf16x8_t*)(hz + (((mrow + 16) * 512 + k0 * 2) ^ swz));
                #pragma unroll
                for (int g = 0; g < 4; ++g) {
                    int row = g * 128 + w * 16 + mrow;
                    bf16x8_t bf = *(const bf16x8_t*)(lds + ((row * 256 + krel * 2) ^ ((row & 7) << 4)));
                    acc[g][0] = __builtin_amdgcn_mfma_f32_16x16x32_bf16(a0, bf, acc[g][0], 0, 0, 0);
                    acc[g][1] = __builtin_amdgcn_mfma_f32_16x16x32_bf16(a1, bf, acc[g][1], 0, 0, 0);
                }
            }
        }

        // ---- gates in-register ----
        float hh[8];
        #pragma unroll
        for (int mh = 0; mh < 2; ++mh)
            #pragma unroll
            for (int r = 0; r < 4; ++r) {
                int j = mh * 4 + r;
                float iv = sigf(acc[0][mh][r] + bf2f(zxv[0][j]));
                float fv = sigf(acc[1][mh][r] + bf2f(zxv[1][j]));
                float gv = tanhf_fast(acc[2][mh][r] + bf2f(zxv[2][j]));
                float ov = sigf(acc[3][mh][r] + bf2f(zxv[3][j]));
                cst[j] = fv * cst[j] + iv * gv;
                hh[j] = ov * tanhf_fast(cst[j]);
            }

        // ---- pack pairs (shfl lane^1); publish tagged + own-h LDS write + Hb ----
        {
            unsigned long long* oslot = hgd + (size_t)(tt & 1) * 4096;
            const int up = (u >> 1);               // global unit-pair index
            const int ue = u & ~1;
            const unsigned long long tagw = (unsigned long long)(tagbase + (unsigned int)tt + 1u);
            #pragma unroll
            for (int j = 0; j < 8; ++j) {
                float ph = __shfl_xor(hh[j], 1);
                unsigned int mine = f2bf(hh[j]), othr = f2bf(ph);
                unsigned int pair = (L & 1) ? ((mine << 16) | othr) : ((othr << 16) | mine);
                if ((L & 1) == (j >> 2)) {
                    int b = (j >> 2) * 16 + (L >> 4) * 4 + (j & 3);
                    __hip_atomic_store(oslot + b * 128 + up,
                                       ((unsigned long long)pair << 32) | tagw,
                                       __ATOMIC_RELAXED, __HIP_MEMORY_SCOPE_AGENT);
                    *(unsigned int*)(hz + ((b * 512 + ue * 2) ^ ((b & 7) << 4))) = pair;
                    *(unsigned int*)(Hb + ((size_t)t * 32 + b) * 512 + d * 256 + ue) = pair;
                }
            }
        }
        __syncthreads();
    }
}

// ---------------- fused attention (bf16 in, bf16 out) ----------------
__global__ __launch_bounds__(256) void attn_fused(
    const unsigned short* __restrict__ qkv, unsigned short* __restrict__ outp)
{
    int s = blockIdx.x & 511;
    int h = blockIdx.x >> 9;
    __shared__ float qs[32][260];
    __shared__ float ks[32][260];
    __shared__ float vs[32][260];
    __shared__ float sc[32][36];
    int tid = threadIdx.x;
    for (int it = 0; it < 32; ++it) {
        const unsigned short* base = qkv + ((size_t)s * 32 + it) * 1536 + h * 256 + tid;
        qs[it][tid] = bf2f(base[0]);
        ks[it][tid] = bf2f(base[512]);
        vs[it][tid] = bf2f(base[1024]);
    }
    __syncthreads();
    int l = tid >> 3, m0 = (tid & 7) * 4;
    float a0 = 0, a1 = 0, a2 = 0, a3 = 0;
    for (int dd = 0; dd < 256; dd += 4) {
        float4 q4 = *(const float4*)&qs[l][dd];
        float4 k0v = *(const float4*)&ks[m0 + 0][dd];
        float4 k1v = *(const float4*)&ks[m0 + 1][dd];
        float4 k2v = *(const float4*)&ks[m0 + 2][dd];
        float4 k3v = *(const float4*)&ks[m0 + 3][dd];
        a0 += q4.x * k0v.x + q4.y * k0v.y + q4.z * k0v.z + q4.w * k0v.w;
        a1 += q4.x * k1v.x + q4.y * k1v.y + q4.z * k1v.z + q4.w * k1v.w;
        a2 += q4.x * k2v.x + q4.y * k2v.y + q4.z * k2v.z + q4.w * k2v.w;
        a3 += q4.x * k3v.x + q4.y * k3v.y + q4.z * k3v.z + q4.w * k3v.w;
    }
    sc[l][m0 + 0] = a0 * 0.0625f;
    sc[l][m0 + 1] = a1 * 0.0625f;
    sc[l][m0 + 2] = a2 * 0.0625f;
    sc[l][m0 + 3] = a3 * 0.0625f;
    __syncthreads();
    if (tid < 32) {
        float mx = -1e30f;
        for (int m = 0; m < 32; ++m) mx = fmaxf(mx, sc[tid][m]);
        float pr[32]; float sm = 0.f;
        for (int m = 0; m < 32; ++m) { pr[m] = __expf(sc[tid][m] - mx); sm += pr[m]; }
        float inv = 1.f / sm;
        for (int m = 0; m < 32; ++m) sc[tid][m] = pr[m] * inv;
    }
    __syncthreads();
    int l2 = tid >> 3, d0 = (tid & 7) * 32;
    float o[32] = {};
    for (int m = 0; m < 32; ++m) {
        float aw = sc[l2][m];
        #pragma unroll
        for (int dd = 0; dd < 32; dd += 4) {
            float4 v4 = *(const float4*)&vs[m][d0 + dd];
            o[dd] += aw * v4.x; o[dd + 1] += aw * v4.y; o[dd + 2] += aw * v4.z; o[dd + 3] += aw * v4.w;
        }
    }
    unsigned short* ob = outp + ((size_t)s * 32 + l2) * 512 + h * 256 + d0;
    #pragma unroll
    for (int dd = 0; dd < 32; dd += 4) {
        ushort4 pv;
        pv.x = f2bf(o[dd]); pv.y = f2bf(o[dd + 1]); pv.z = f2bf(o[dd + 2]); pv.w = f2bf(o[dd + 3]);
        *(ushort4*)(ob + dd) = pv;
    }
}

// ---------------- fc logits (A f32) ----------------
__global__ __launch_bounds__(256) void fc_logits(
    const float* __restrict__ A, const float* __restrict__ fcw, const float* __restrict__ fcb,
    float* __restrict__ outp)
{
    __shared__ float wsm[16][516];
    int tid = threadIdx.x;
    for (int idx = tid; idx < 8192; idx += 256) wsm[idx >> 9][idx & 511] = fcw[idx];
    __syncthreads();
    int r = blockIdx.x * 16 + (tid >> 4);
    int c = tid & 15;
    const float* ar = A + (size_t)r * 512;
    float acc = 0.f;
    for (int k = 0; k < 512; k += 4) {
        float4 a4 = *(const float4*)(ar + k);
        float4 w4 = *(const float4*)&wsm[c][k];
        acc += a4.x * w4.x + a4.y * w4.y + a4.z * w4.z + a4.w * w4.w;
    }
    int s = r >> 5, b = r & 31;
    outp[(size_t)b * 8192 + s * 16 + c] = acc + fcb[c];
}

// ---------------- CRF ----------------
__global__ __launch_bounds__(256) void crf_forward(
    const float* __restrict__ em, const int* __restrict__ labels,
    const float* __restrict__ cs, const float* __restrict__ ce, const float* __restrict__ ct,
    float* __restrict__ res)
{
    int b = blockIdx.x;
    int tid = threadIdx.x;
    int jj = tid >> 4, ii = tid & 15;
    __shared__ float trans[16][17];
    __shared__ float alpha[2][16];
    __shared__ float red[256];
    trans[tid >> 4][tid & 15] = ct[tid & 255];
    const float* emb_ = em + (size_t)b * 8192;
    const int* tg = labels + b * 512;
    float part = 0.f;
    for (int t = tid; t < 512; t += 256) {
        int cur = tg[t];
        part += emb_[t * 16 + cur] + (t == 0 ? cs[cur] : ct[tg[t - 1] * 16 + cur]);
    }
    red[tid] = part;
    if (tid < 16) alpha[0][tid] = cs[tid] + emb_[tid];
    __syncthreads();
    for (int off = 128; off > 0; off >>= 1) {
        if (tid < off) red[tid] += red[tid + off];
        __syncthreads();
    }
    for (int t = 1; t < 512; ++t) {
        int p = t & 1;
        float v = alpha[p ^ 1][ii] + trans[ii][jj];
        float mx = v;
        mx = fmaxf(mx, __shfl_xor(mx, 1));
        mx = fmaxf(mx, __shfl_xor(mx, 2));
        mx = fmaxf(mx, __shfl_xor(mx, 4));
        mx = fmaxf(mx, __shfl_xor(mx, 8));
        float e = __expf(v - mx);
        e += __shfl_xor(e, 1); e += __shfl_xor(e, 2); e += __shfl_xor(e, 4); e += __shfl_xor(e, 8);
        if (ii == 0) alpha[p][jj] = mx + __logf(e) + emb_[t * 16 + jj];
        __syncthreads();
    }
    if (tid == 0) {
        float mx = -1e30f;
        for (int c2 = 0; c2 < 16; ++c2) mx = fmaxf(mx, alpha[1][c2] + ce[c2]);
        float sm = 0.f;
        for (int c2 = 0; c2 < 16; ++c2) sm += __expf(alpha[1][c2] + ce[c2] - mx);
        float logZ = mx + __logf(sm);
        float score = red[0] + ce[tg[511]];
        res[b] = logZ - score;
    }
}

__global__ void crf_final(const float* __restrict__ res, float* __restrict__ nll)
{
    if (threadIdx.x == 0) {
        float s2 = 0.f;
        for (int b = 0; b < 32; ++b) s2 += res[b];
        nll[0] = s2;
    }
}

extern "C" void kernel_launch(void* const* d_in, const int* in_sizes, int n_in,
                              void* d_out, int out_size, void* d_ws, size_t ws_size,
                              hipStream_t stream)
{
    const int* x      = (const int*)d_in[0];
    const int* labels = (const int*)d_in[1];
    const float* emb  = (const float*)d_in[2];
    const float* wih  = (const float*)d_in[3];
    const float* whh  = (const float*)d_in[4];
    const float* bih  = (const float*)d_in[5];
    const float* bhh  = (const float*)d_in[6];
    const float* inw  = (const float*)d_in[7];
    const float* inb  = (const float*)d_in[8];
    const float* opw  = (const float*)d_in[9];
    const float* opb  = (const float*)d_in[10];
    const float* fcw  = (const float*)d_in[11];
    const float* fcb  = (const float*)d_in[12];
    const float* cs   = (const float*)d_in[13];
    const float* ce   = (const float*)d_in[14];
    const float* ct   = (const float*)d_in[15];
    float* out = (float*)d_out;

    // ws layout (MiB):
    //  [0,16)    Xb (embed out)       -> attnO (after qkv consumed)
    //  [16,48)   H0b [16,32)          -> OPout f32 [16,48); res at 16M (CRF)
    //  [32,48)   H1b
    //  [48,112)  Zfb [48,80), Zbb [80,112)   -> qkv [48,96)
    //  [112,120) wihb [112,116), whhb [116,118), inwb [118,119.5), opwb [119.5,120)
    //  [120,...) hg (128 KB tagged h-exchange)
    char* ws = (char*)d_ws;
    const size_t MiB = 1ull << 20;
    unsigned short* Xb    = (unsigned short*)(ws);
    unsigned short* attnO = (unsigned short*)(ws);
    unsigned short* H0b   = (unsigned short*)(ws + 16 * MiB);
    float*          OPout = (float*)(ws + 16 * MiB);
    float*          res   = (float*)(ws + 16 * MiB);
    unsigned short* H1b   = (unsigned short*)(ws + 32 * MiB);
    unsigned short* Zfb   = (unsigned short*)(ws + 48 * MiB);
    unsigned short* qkv   = (unsigned short*)(ws + 48 * MiB);
    unsigned short* Zbb   = (unsigned short*)(ws + 80 * MiB);
    unsigned short* wihb  = (unsigned short*)(ws + 112 * MiB);
    unsigned short* whhb  = (unsigned short*)(ws + 116 * MiB);
    unsigned short* inwb  = (unsigned short*)(ws + 118 * MiB);
    unsigned short* opwb  = (unsigned short*)(ws + 119 * MiB + 512 * 1024);
    unsigned long long* hg = (unsigned long long*)(ws + 120 * MiB);

    // 1) embedding gather + weight conversions + h-exchange zeroing
    embed_gather<<<16384, 128, 0, stream>>>(x, emb, Xb);
    conv_f2b<<<2048, 256, 0, stream>>>(wih, wihb, 2097152);
    conv_f2b<<<1024, 256, 0, stream>>>(whh, whhb, 1048576);
    conv_f2b<<<768, 256, 0, stream>>>(inw, inwb, 786432);
    conv_f2b<<<256, 256, 0, stream>>>(opw, opwb, 262144);
    zero_ws<<<128, 256, 0, stream>>>((unsigned int*)hg, 32768);

    // 2) two BiLSTM layers
    for (int l = 0; l < 2; ++l) {
        const unsigned short* Ain = l ? H0b : Xb;
        unsigned short* Ho        = l ? H1b : H0b;
        for (int dd = 0; dd < 2; ++dd) {
            gemm_bf16<1><<<dim3(256, 16), 256, 0, stream>>>(
                Ain, wihb + (size_t)(l * 2 + dd) * 524288,
                bih + (l * 2 + dd) * 1024, bhh + (l * 2 + dd) * 1024,
                dd ? (void*)Zbb : (void*)Zfb, 16384, 1024, 512);
        }
        lstm_rec3<<<4, 512, 0, stream>>>(
            Zfb, Zbb, whhb + (size_t)l * 524288, hg, (unsigned int)(l * 512), Ho);
    }

    // 3) MHA
    gemm_bf16<1><<<dim3(256, 24), 256, 0, stream>>>(H1b, inwb, inb, nullptr, (void*)qkv, 16384, 1536, 512);
    attn_fused<<<1024, 256, 0, stream>>>(qkv, attnO);
    gemm_bf16<0><<<dim3(256, 8), 256, 0, stream>>>(attnO, opwb, opb, nullptr, (void*)OPout, 16384, 512, 512);

    // 4) logits -> d_out
    fc_logits<<<1024, 256, 0, stream>>>(OPout, fcw, fcb, out);

    // 5) CRF
    crf_forward<<<32, 256, 0, stream>>>(out, labels, cs, ce, ct, res);
    crf_final<<<1, 64, 0, stream>>>(res, out + 262144);

    (void)in_sizes; (void)n_in; (void)out_size; (void)ws_size;
}